// Round 1
// baseline (315.935 us; speedup 1.0000x reference)
//
#include <hip/hip_runtime.h>
#include <cstdint>
#include <cstddef>

#define D_MODEL 768
#define N_HEADS 12
#define HEAD_DIM 64
#define CHUNK_SZ 512
#define N_LM 32
#define BATCH 2
#define SEQ 8192
#define N_CH 16
#define SEG 256
#define TOK (BATCH*SEQ)      /* 16384 */
#define MKV_PAD 16512        /* 16384 + 64 landmarks + 64 zero pad -> 129*128 */

typedef unsigned short u16;
typedef __attribute__((ext_vector_type(8))) __bf16 bf16x8;
typedef __attribute__((ext_vector_type(4))) float f32x4;

__device__ __forceinline__ u16 f2bf(float f){
  unsigned u = __float_as_uint(f);
  u += 0x7fffu + ((u >> 16) & 1u);
  return (u16)(u >> 16);
}

// ---------------- f32 -> bf16 convert (grid-stride over float4) ----------------
__global__ void cvt_bf16_kernel(const float* __restrict__ src, u16* __restrict__ dst, int n4){
  int stride = gridDim.x * blockDim.x;
  for (int i = blockIdx.x*blockDim.x + threadIdx.x; i < n4; i += stride){
    float4 v = reinterpret_cast<const float4*>(src)[i];
    ushort4 o;
    o.x = f2bf(v.x); o.y = f2bf(v.y); o.z = f2bf(v.z); o.w = f2bf(v.w);
    reinterpret_cast<ushort4*>(dst)[i] = o;
  }
}

// ---- xcat rows [0,TOK) = bf16(x); rows [TOK,MKV_PAD) = 0 (landmarks overwritten later)
__global__ void build_xcat_kernel(const float* __restrict__ x, u16* __restrict__ xcat){
  const int total4 = MKV_PAD * D_MODEL / 4;
  const int x4 = TOK * D_MODEL / 4;
  int stride = gridDim.x * blockDim.x;
  for (int i = blockIdx.x*blockDim.x + threadIdx.x; i < total4; i += stride){
    ushort4 o;
    if (i < x4){
      float4 v = reinterpret_cast<const float4*>(x)[i];
      o.x = f2bf(v.x); o.y = f2bf(v.y); o.z = f2bf(v.z); o.w = f2bf(v.w);
    } else { o.x = 0; o.y = 0; o.z = 0; o.w = 0; }
    reinterpret_cast<ushort4*>(xcat)[i] = o;
  }
}

// ---------------- landmark mean-pool: 64 blocks = (b,l) ----------------
__global__ __launch_bounds__(256) void landmark_kernel(const float* __restrict__ x, u16* __restrict__ xcat){
  int b = blockIdx.x >> 5, l = blockIdx.x & 31;
  const float* base = x + ((size_t)b*SEQ + (size_t)l*SEG) * D_MODEL;
  int d = threadIdx.x;
  float a0=0.f, a1=0.f, a2=0.f;
  for (int tt=0; tt<SEG; ++tt){
    const float* row = base + (size_t)tt*D_MODEL;
    a0 += row[d]; a1 += row[d+256]; a2 += row[d+512];
  }
  u16* orow = xcat + ((size_t)TOK + (size_t)b*N_LM + l) * D_MODEL;
  const float inv = 1.f/(float)SEG;
  orow[d] = f2bf(a0*inv); orow[d+256] = f2bf(a1*inv); orow[d+512] = f2bf(a2*inv);
}

// ---------------- bf16 GEMM: C[M][768] = A[M][768] * Bt[768][768]^T + bias ----------------
// grid (M/128, 6), 256 threads (4 waves as 2x2 of 64x64), BK=64, LDS padded to 72.
template<int OUT_F32>
__global__ __launch_bounds__(256) void gemm_bt_kernel(
    const u16* __restrict__ A, const u16* __restrict__ Bt,
    const float* __restrict__ bias, void* __restrict__ Cout)
{
  __shared__ u16 As[128][72];
  __shared__ u16 Bs[128][72];
  const int t = threadIdx.x;
  const int lane = t & 63, wid = t >> 6;
  const int wr = wid >> 1, wc = wid & 1;
  const int lr = lane & 15, lg = lane >> 4;
  const size_t row0 = (size_t)blockIdx.x * 128;
  const int col0 = blockIdx.y * 128;

  f32x4 acc[4][4];
  #pragma unroll
  for (int m=0;m<4;m++)
    #pragma unroll
    for (int n=0;n<4;n++) acc[m][n] = f32x4{0.f,0.f,0.f,0.f};

  const int sc = (t & 7) << 3;
  const int sr0 = t >> 3;

  for (int ko = 0; ko < D_MODEL; ko += 64){
    #pragma unroll
    for (int i=0;i<4;i++){
      int r = sr0 + i*32;
      *reinterpret_cast<float4*>(&As[r][sc]) =
        *reinterpret_cast<const float4*>(&A[(row0 + r)*D_MODEL + ko + sc]);
      *reinterpret_cast<float4*>(&Bs[r][sc]) =
        *reinterpret_cast<const float4*>(&Bt[((size_t)col0 + r)*D_MODEL + ko + sc]);
    }
    __syncthreads();
    #pragma unroll
    for (int kk=0;kk<2;kk++){
      bf16x8 af[4], bv[4];
      #pragma unroll
      for (int m=0;m<4;m++)
        af[m] = *reinterpret_cast<const bf16x8*>(&As[wr*64 + m*16 + lr][kk*32 + lg*8]);
      #pragma unroll
      for (int n=0;n<4;n++)
        bv[n] = *reinterpret_cast<const bf16x8*>(&Bs[wc*64 + n*16 + lr][kk*32 + lg*8]);
      #pragma unroll
      for (int m=0;m<4;m++)
        #pragma unroll
        for (int n=0;n<4;n++)
          acc[m][n] = __builtin_amdgcn_mfma_f32_16x16x32_bf16(af[m], bv[n], acc[m][n], 0, 0, 0);
    }
    __syncthreads();
  }

  #pragma unroll
  for (int m=0;m<4;m++){
    #pragma unroll
    for (int n=0;n<4;n++){
      const int col = col0 + wc*64 + n*16 + lr;
      const float bcol = bias[col];
      #pragma unroll
      for (int e=0;e<4;e++){
        size_t row = row0 + wr*64 + m*16 + lg*4 + e;
        float val = acc[m][n][e] + bcol;
        if (OUT_F32) reinterpret_cast<float*>(Cout)[row*D_MODEL + col] = val;
        else         reinterpret_cast<u16*>(Cout)[row*D_MODEL + col] = f2bf(val);
      }
    }
  }
}

// ---------------- attention tile helper (NK = 32 landmark tile or 64 local tile) ----------------
template<int NK>
__device__ __forceinline__ void attn_tile(
    size_t krow0, int h, int lr, int lg, int t,
    const u16* __restrict__ Kb, const u16* __restrict__ Vb,
    u16 (* __restrict__ Ks)[72], u16 (* __restrict__ Vts)[72], u16 (* __restrict__ Pw)[72],
    const bf16x8 (&qf)[2][2], float (&m_run)[2][4], float (&l_run)[2][4], f32x4 (&of)[2][4])
{
  constexpr int NCF = NK/16;   // S col fragments
  constexpr int NKT = NK/32;   // PV K steps
  // stage K (row-major, padded) and V^T (scatter)
  #pragma unroll
  for (int i=0; i<NK/32; ++i){
    int idx = t + i*256;
    int key = idx >> 3;
    int c = (idx & 7) << 3;
    size_t goff = (krow0 + (size_t)key)*D_MODEL + (size_t)h*HEAD_DIM + c;
    *reinterpret_cast<float4*>(&Ks[key][c]) = *reinterpret_cast<const float4*>(&Kb[goff]);
    float4 vv = *reinterpret_cast<const float4*>(&Vb[goff]);
    union { float4 f; u16 u[8]; } uu; uu.f = vv;
    #pragma unroll
    for (int j=0;j<8;j++) Vts[c+j][key] = uu.u[j];
  }
  __syncthreads();

  // S = Q K^T
  f32x4 sf[2][NCF];
  #pragma unroll
  for (int c=0;c<NCF;c++){
    bf16x8 kf0 = *reinterpret_cast<const bf16x8*>(&Ks[c*16 + lr][0*32 + lg*8]);
    bf16x8 kf1 = *reinterpret_cast<const bf16x8*>(&Ks[c*16 + lr][1*32 + lg*8]);
    #pragma unroll
    for (int r=0;r<2;r++){
      f32x4 s = f32x4{0.f,0.f,0.f,0.f};
      s = __builtin_amdgcn_mfma_f32_16x16x32_bf16(qf[r][0], kf0, s, 0,0,0);
      s = __builtin_amdgcn_mfma_f32_16x16x32_bf16(qf[r][1], kf1, s, 0,0,0);
      sf[r][c] = s;
    }
  }
  #pragma unroll
  for (int r=0;r<2;r++)
    #pragma unroll
    for (int c=0;c<NCF;c++)
      #pragma unroll
      for (int e=0;e<4;e++) sf[r][c][e] *= 0.125f;  // 1/sqrt(64)

  // online softmax (row lives on 16 lanes sharing lane>>4; reduce over lane&15)
  #pragma unroll
  for (int r=0;r<2;r++){
    #pragma unroll
    for (int e=0;e<4;e++){
      float mt = sf[r][0][e];
      #pragma unroll
      for (int c=1;c<NCF;c++) mt = fmaxf(mt, sf[r][c][e]);
      #pragma unroll
      for (int msk=1; msk<16; msk<<=1) mt = fmaxf(mt, __shfl_xor(mt, msk, 64));
      float newm = fmaxf(m_run[r][e], mt);
      float alpha = __expf(m_run[r][e] - newm);
      float rs = 0.f;
      #pragma unroll
      for (int c=0;c<NCF;c++){
        float p = __expf(sf[r][c][e] - newm);
        sf[r][c][e] = p;
        rs += p;
      }
      #pragma unroll
      for (int msk=1; msk<16; msk<<=1) rs += __shfl_xor(rs, msk, 64);
      l_run[r][e] = l_run[r][e]*alpha + rs;
      m_run[r][e] = newm;
      #pragma unroll
      for (int c=0;c<4;c++) of[r][c][e] *= alpha;
    }
  }

  // P (C-layout) -> per-wave LDS -> A-layout fragments
  #pragma unroll
  for (int r=0;r<2;r++)
    #pragma unroll
    for (int c=0;c<NCF;c++)
      #pragma unroll
      for (int e=0;e<4;e++)
        Pw[r*16 + lg*4 + e][c*16 + lr] = f2bf(sf[r][c][e]);

  // O += P V
  #pragma unroll
  for (int kt=0; kt<NKT; ++kt){
    bf16x8 pf[2];
    #pragma unroll
    for (int r=0;r<2;r++)
      pf[r] = *reinterpret_cast<const bf16x8*>(&Pw[r*16 + lr][kt*32 + lg*8]);
    #pragma unroll
    for (int c=0;c<4;c++){
      bf16x8 vf = *reinterpret_cast<const bf16x8*>(&Vts[c*16 + lr][kt*32 + lg*8]);
      #pragma unroll
      for (int r=0;r<2;r++)
        of[r][c] = __builtin_amdgcn_mfma_f32_16x16x32_bf16(pf[r], vf, of[r][c], 0,0,0);
    }
  }
  __syncthreads();
}

// ---------------- attention: grid (4 qtiles, 12 heads, 32 b*chunk), 256 thr ----------------
__global__ __launch_bounds__(256) void attn_kernel(
    const u16* __restrict__ Qb, const u16* __restrict__ Kb,
    const u16* __restrict__ Vb, u16* __restrict__ AO)
{
  __shared__ u16 Qs[128][72];
  __shared__ u16 Ks[64][72];
  __shared__ u16 Vts[64][72];
  __shared__ u16 Ps[4][32][72];

  const int t = threadIdx.x;
  const int lane = t & 63, w = t >> 6;
  const int lr = lane & 15, lg = lane >> 4;
  const int qt = blockIdx.x;
  const int h  = blockIdx.y;
  const int b  = blockIdx.z >> 4, ch = blockIdx.z & 15;
  const size_t tok0 = (size_t)b*SEQ + (size_t)ch*CHUNK_SZ + (size_t)qt*128;

  { // stage Q tile 128x64
    int sc = (t & 7) << 3;
    int sr0 = t >> 3;
    #pragma unroll
    for (int i=0;i<4;i++){
      int r = sr0 + i*32;
      *reinterpret_cast<float4*>(&Qs[r][sc]) =
        *reinterpret_cast<const float4*>(&Qb[(tok0 + r)*D_MODEL + (size_t)h*HEAD_DIM + sc]);
    }
  }
  __syncthreads();

  bf16x8 qf[2][2];
  #pragma unroll
  for (int r=0;r<2;r++)
    #pragma unroll
    for (int kk=0;kk<2;kk++)
      qf[r][kk] = *reinterpret_cast<const bf16x8*>(&Qs[w*32 + r*16 + lr][kk*32 + lg*8]);

  float m_run[2][4], l_run[2][4];
  f32x4 of[2][4];
  #pragma unroll
  for (int r=0;r<2;r++)
    #pragma unroll
    for (int e=0;e<4;e++){ m_run[r][e] = -INFINITY; l_run[r][e] = 0.f; }
  #pragma unroll
  for (int r=0;r<2;r++)
    #pragma unroll
    for (int c=0;c<4;c++) of[r][c] = f32x4{0.f,0.f,0.f,0.f};

  // landmark tile (32 keys), then 8 local tiles (64 keys each)
  attn_tile<32>((size_t)TOK + (size_t)b*N_LM, h, lr, lg, t, Kb, Vb, Ks, Vts, Ps[w], qf, m_run, l_run, of);
  for (int tl=0; tl<8; ++tl)
    attn_tile<64>((size_t)b*SEQ + (size_t)ch*CHUNK_SZ + (size_t)tl*64, h, lr, lg, t, Kb, Vb, Ks, Vts, Ps[w], qf, m_run, l_run, of);

  #pragma unroll
  for (int r=0;r<2;r++)
    #pragma unroll
    for (int c=0;c<4;c++)
      #pragma unroll
      for (int e=0;e<4;e++){
        int row = r*16 + lg*4 + e;
        float val = of[r][c][e] / l_run[r][e];
        AO[(tok0 + w*32 + row)*D_MODEL + (size_t)h*HEAD_DIM + c*16 + lr] = f2bf(val);
      }
}

// ---------------- launch ----------------
extern "C" void kernel_launch(void* const* d_in, const int* in_sizes, int n_in,
                              void* d_out, int out_size, void* d_ws, size_t ws_size,
                              hipStream_t stream) {
  const float* x  = (const float*)d_in[0];
  const float* Wq = (const float*)d_in[1];
  const float* bq = (const float*)d_in[2];
  const float* Wk = (const float*)d_in[3];
  const float* bk = (const float*)d_in[4];
  const float* Wv = (const float*)d_in[5];
  const float* bv = (const float*)d_in[6];
  const float* Wo = (const float*)d_in[7];
  const float* bo = (const float*)d_in[8];
  float* out = (float*)d_out;

  // workspace layout (bytes)
  const size_t XCAT_OFF = 0;                       // 16512*768*2 = 25362432
  const size_t Q_OFF    = 25362432;                // 16384*768*2 = 25165824
  const size_t K_OFF    = 50528256;                // 25362432
  const size_t V_OFF    = 75890688;                // 25362432
  const size_t AO_OFF   = 101253120;               // 25165824
  const size_t WQ_OFF   = 126418944;               // 1179648
  const size_t WK_OFF   = 127598592;
  const size_t WV_OFF   = 128778240;
  const size_t WO_OFF   = 129957888;
  const size_t TOTAL    = 131137536;
  if (ws_size < TOTAL) return;

  char* ws = (char*)d_ws;
  u16* xcat = (u16*)(ws + XCAT_OFF);
  u16* Qb   = (u16*)(ws + Q_OFF);
  u16* Kb   = (u16*)(ws + K_OFF);
  u16* Vb   = (u16*)(ws + V_OFF);
  u16* AO   = (u16*)(ws + AO_OFF);
  u16* wqb  = (u16*)(ws + WQ_OFF);
  u16* wkb  = (u16*)(ws + WK_OFF);
  u16* wvb  = (u16*)(ws + WV_OFF);
  u16* wob  = (u16*)(ws + WO_OFF);

  dim3 blk(256);
  const int wn4 = D_MODEL*D_MODEL/4;  // 147456
  cvt_bf16_kernel<<<dim3(576), blk, 0, stream>>>(Wq, wqb, wn4);
  cvt_bf16_kernel<<<dim3(576), blk, 0, stream>>>(Wk, wkb, wn4);
  cvt_bf16_kernel<<<dim3(576), blk, 0, stream>>>(Wv, wvb, wn4);
  cvt_bf16_kernel<<<dim3(576), blk, 0, stream>>>(Wo, wob, wn4);

  build_xcat_kernel<<<dim3(4096), blk, 0, stream>>>(x, xcat);
  landmark_kernel<<<dim3(64), blk, 0, stream>>>(x, xcat);

  gemm_bt_kernel<0><<<dim3(128, 6), blk, 0, stream>>>(xcat, wqb, bq, (void*)Qb);
  gemm_bt_kernel<0><<<dim3(129, 6), blk, 0, stream>>>(xcat, wkb, bk, (void*)Kb);
  gemm_bt_kernel<0><<<dim3(129, 6), blk, 0, stream>>>(xcat, wvb, bv, (void*)Vb);

  attn_kernel<<<dim3(4, 12, 32), blk, 0, stream>>>(Qb, Kb, Vb, AO);

  gemm_bt_kernel<1><<<dim3(128, 6), blk, 0, stream>>>(AO, wob, bo, (void*)out);
}

// Round 2
// 250.463 us; speedup vs baseline: 1.2614x; 1.2614x over previous
//
#include <hip/hip_runtime.h>
#include <cstdint>
#include <cstddef>

#define D_MODEL 768
#define N_HEADS 12
#define HEAD_DIM 64
#define CHUNK_SZ 512
#define N_LM 32
#define BATCH 2
#define SEQ 8192
#define N_CH 16
#define SEG 256
#define TOK (BATCH*SEQ)      /* 16384 */
#define MKV_PAD 16512        /* 16384 + 64 lm/pad rows -> 129*128 */
#define QSCALE 0.18033688011112042f  /* 0.125 * log2(e): softmax done in exp2 domain */

typedef unsigned short u16;
typedef __attribute__((ext_vector_type(8))) __bf16 bf16x8;
typedef __attribute__((ext_vector_type(4))) float f32x4;

__device__ __forceinline__ u16 f2bf(float f){
  unsigned u = __float_as_uint(f);
  u += 0x7fffu + ((u >> 16) & 1u);
  return (u16)(u >> 16);
}

// ---------------- all 4 weight converts in one launch ----------------
__global__ __launch_bounds__(256) void cvt4_kernel(
    const float* __restrict__ w0, const float* __restrict__ w1,
    const float* __restrict__ w2, const float* __restrict__ w3,
    u16* __restrict__ o0, u16* __restrict__ o1, u16* __restrict__ o2, u16* __restrict__ o3)
{
  const int n4 = D_MODEL*D_MODEL/4;   // 147456, divisible by 256 -> sel uniform per block
  int i = blockIdx.x*256 + threadIdx.x;
  int sel = i / n4, j = i - sel*n4;
  const float* s = sel==0 ? w0 : sel==1 ? w1 : sel==2 ? w2 : w3;
  u16* o = sel==0 ? o0 : sel==1 ? o1 : sel==2 ? o2 : o3;
  float4 v = reinterpret_cast<const float4*>(s)[j];
  ushort4 p; p.x=f2bf(v.x); p.y=f2bf(v.y); p.z=f2bf(v.z); p.w=f2bf(v.w);
  reinterpret_cast<ushort4*>(o)[j] = p;
}

// ---- xcat rows [0,TOK) = bf16(x); rows [TOK,MKV_PAD) = 0 (landmarks overwritten later)
__global__ void build_xcat_kernel(const float* __restrict__ x, u16* __restrict__ xcat){
  const int total4 = MKV_PAD * D_MODEL / 4;
  const int x4 = TOK * D_MODEL / 4;
  int stride = gridDim.x * blockDim.x;
  for (int i = blockIdx.x*blockDim.x + threadIdx.x; i < total4; i += stride){
    ushort4 o;
    if (i < x4){
      float4 v = reinterpret_cast<const float4*>(x)[i];
      o.x = f2bf(v.x); o.y = f2bf(v.y); o.z = f2bf(v.z); o.w = f2bf(v.w);
    } else { o.x = 0; o.y = 0; o.z = 0; o.w = 0; }
    reinterpret_cast<ushort4*>(xcat)[i] = o;
  }
}

// ---------------- landmark mean-pool: 64 blocks = (b,l) ----------------
__global__ __launch_bounds__(256) void landmark_kernel(const float* __restrict__ x, u16* __restrict__ xcat){
  int b = blockIdx.x >> 5, l = blockIdx.x & 31;
  const float* base = x + ((size_t)b*SEQ + (size_t)l*SEG) * D_MODEL;
  int d = threadIdx.x;
  float a0=0.f, a1=0.f, a2=0.f;
  for (int tt=0; tt<SEG; ++tt){
    const float* row = base + (size_t)tt*D_MODEL;
    a0 += row[d]; a1 += row[d+256]; a2 += row[d+512];
  }
  u16* orow = xcat + ((size_t)TOK + (size_t)b*N_LM + l) * D_MODEL;
  const float inv = 1.f/(float)SEG;
  orow[d] = f2bf(a0*inv); orow[d+256] = f2bf(a1*inv); orow[d+512] = f2bf(a2*inv);
}

// ---------------- bf16 GEMM: C[M][N] = A[M][768] * Bt[N][768]^T, C += bias; *scale ----------------
// grid (M/128, N/128), 256 threads (2x2 waves of 64x64), BK=64, LDS pad 72.
// BIAS_ROW: bias indexed by output row (for the V^T = Wv * xcat^T call), else by col.
template<int OUT_F32, int BIAS_ROW>
__global__ __launch_bounds__(256) void gemm_bt_kernel(
    const u16* __restrict__ A, const u16* __restrict__ Bt,
    const float* __restrict__ bias, void* __restrict__ Cout, int ldc, float scale)
{
  __shared__ u16 As[128][72];
  __shared__ u16 Bs[128][72];
  const int t = threadIdx.x;
  const int lane = t & 63, wid = t >> 6;
  const int wr = wid >> 1, wc = wid & 1;
  const int lr = lane & 15, lg = lane >> 4;
  const size_t row0 = (size_t)blockIdx.x * 128;
  const int col0 = blockIdx.y * 128;

  f32x4 acc[4][4];
  #pragma unroll
  for (int m=0;m<4;m++)
    #pragma unroll
    for (int n=0;n<4;n++) acc[m][n] = f32x4{0.f,0.f,0.f,0.f};

  const int sc = (t & 7) << 3;
  const int sr0 = t >> 3;

  for (int ko = 0; ko < D_MODEL; ko += 64){
    #pragma unroll
    for (int i=0;i<4;i++){
      int r = sr0 + i*32;
      *reinterpret_cast<float4*>(&As[r][sc]) =
        *reinterpret_cast<const float4*>(&A[(row0 + r)*D_MODEL + ko + sc]);
      *reinterpret_cast<float4*>(&Bs[r][sc]) =
        *reinterpret_cast<const float4*>(&Bt[((size_t)col0 + r)*D_MODEL + ko + sc]);
    }
    __syncthreads();
    #pragma unroll
    for (int kk=0;kk<2;kk++){
      bf16x8 af[4], bv[4];
      #pragma unroll
      for (int m=0;m<4;m++)
        af[m] = *reinterpret_cast<const bf16x8*>(&As[wr*64 + m*16 + lr][kk*32 + lg*8]);
      #pragma unroll
      for (int n=0;n<4;n++)
        bv[n] = *reinterpret_cast<const bf16x8*>(&Bs[wc*64 + n*16 + lr][kk*32 + lg*8]);
      #pragma unroll
      for (int m=0;m<4;m++)
        #pragma unroll
        for (int n=0;n<4;n++)
          acc[m][n] = __builtin_amdgcn_mfma_f32_16x16x32_bf16(af[m], bv[n], acc[m][n], 0, 0, 0);
    }
    __syncthreads();
  }

  #pragma unroll
  for (int m=0;m<4;m++){
    #pragma unroll
    for (int n=0;n<4;n++){
      const int col = col0 + wc*64 + n*16 + lr;
      const float bcol = BIAS_ROW ? 0.f : bias[col];
      #pragma unroll
      for (int e=0;e<4;e++){
        size_t row = row0 + wr*64 + m*16 + lg*4 + e;
        float b = BIAS_ROW ? bias[row] : bcol;
        float val = (acc[m][n][e] + b) * scale;
        if (OUT_F32) reinterpret_cast<float*>(Cout)[row*(size_t)ldc + col] = val;
        else         reinterpret_cast<u16*>(Cout)[row*(size_t)ldc + col] = f2bf(val);
      }
    }
  }
}

// ---------------- attention compute for one staged KV tile ----------------
// S^T = mfma(K, Q): col=q=lr, row=key. O^T = mfma(V^T, P): col=q=lr, row=d.
// Softmax per q lives on 4 lanes {lr, lr+16, lr+32, lr+48}: in-reg reduce + 2 shfl_xor.
template<int NK>
__device__ __forceinline__ void attn_compute(
    int lr, int lg,
    const u16 (* __restrict__ Ks)[72], const u16 (* __restrict__ Vs)[72],
    u16 (* __restrict__ Pw)[72],
    const bf16x8 (&qf)[2][2], float (&m_run)[2], float (&l_run)[2], f32x4 (&of)[2][4])
{
  constexpr int NCF = NK/16;   // S^T row fragments
  constexpr int NKT = NK/32;   // PV K steps

  // S^T = K Q^T  (both operands: contiguous-K row reads from LDS/regs)
  f32x4 s2[2][NCF];
  #pragma unroll
  for (int c=0;c<NCF;c++){
    bf16x8 kf0 = *reinterpret_cast<const bf16x8*>(&Ks[c*16 + lr][lg*8]);
    bf16x8 kf1 = *reinterpret_cast<const bf16x8*>(&Ks[c*16 + lr][32 + lg*8]);
    #pragma unroll
    for (int r=0;r<2;r++){
      f32x4 s = f32x4{0.f,0.f,0.f,0.f};
      s = __builtin_amdgcn_mfma_f32_16x16x32_bf16(kf0, qf[r][0], s, 0,0,0);
      s = __builtin_amdgcn_mfma_f32_16x16x32_bf16(kf1, qf[r][1], s, 0,0,0);
      s2[r][c] = s;
    }
  }

  // V fragments (A-operand rows = d)
  bf16x8 vf[NKT][4];
  #pragma unroll
  for (int kt=0;kt<NKT;kt++)
    #pragma unroll
    for (int c=0;c<4;c++)
      vf[kt][c] = *reinterpret_cast<const bf16x8*>(&Vs[c*16 + lr][kt*32 + lg*8]);

  #pragma unroll
  for (int r=0;r<2;r++){
    // tile max (exp2 domain; Q pre-scaled by 0.125*log2e)
    float tm = s2[r][0][0];
    #pragma unroll
    for (int c=0;c<NCF;c++)
      #pragma unroll
      for (int e=0;e<4;e++) tm = fmaxf(tm, s2[r][c][e]);
    tm = fmaxf(tm, __shfl_xor(tm, 16, 64));
    tm = fmaxf(tm, __shfl_xor(tm, 32, 64));
    float mnew = fmaxf(m_run[r], tm);
    float al = exp2f(m_run[r] - mnew);
    float ts = 0.f;
    #pragma unroll
    for (int c=0;c<NCF;c++)
      #pragma unroll
      for (int e=0;e<4;e++){
        float p = exp2f(s2[r][c][e] - mnew);
        s2[r][c][e] = p;
        ts += p;
      }
    ts += __shfl_xor(ts, 16, 64);
    ts += __shfl_xor(ts, 32, 64);
    l_run[r] = l_run[r]*al + ts;
    m_run[r] = mnew;
    #pragma unroll
    for (int c=0;c<4;c++)
      #pragma unroll
      for (int e=0;e<4;e++) of[r][c][e] *= al;

    // P^T regs -> P[q][key] in per-wave LDS (vectorized b64 writes)
    #pragma unroll
    for (int c=0;c<NCF;c++){
      ushort4 pk;
      pk.x = f2bf(s2[r][c][0]); pk.y = f2bf(s2[r][c][1]);
      pk.z = f2bf(s2[r][c][2]); pk.w = f2bf(s2[r][c][3]);
      *reinterpret_cast<ushort4*>(&Pw[lr][c*16 + lg*4]) = pk;
    }
    // O^T += V^T P  (within-wave P bounce; compiler inserts lgkmcnt)
    #pragma unroll
    for (int kt=0;kt<NKT;kt++){
      bf16x8 pf = *reinterpret_cast<const bf16x8*>(&Pw[lr][kt*32 + lg*8]);
      #pragma unroll
      for (int c=0;c<4;c++)
        of[r][c] = __builtin_amdgcn_mfma_f32_16x16x32_bf16(vf[kt][c], pf, of[r][c], 0,0,0);
    }
  }
}

// ---------------- attention: grid (4 qtiles, 12 heads, 32 b*chunk), 256 thr ----------------
__global__ __launch_bounds__(256) void attn_kernel(
    const u16* __restrict__ Qb, const u16* __restrict__ Kb,
    const u16* __restrict__ Vt, u16* __restrict__ AO)
{
  __shared__ u16 Ks[64][72];
  __shared__ u16 Vs[64][72];
  __shared__ u16 PwAll[4][16][72];

  const int t = threadIdx.x;
  const int lane = t & 63, w = t >> 6;
  const int lr = lane & 15, lg = lane >> 4;
  const int qt = blockIdx.x;
  const int h  = blockIdx.y;
  const int b  = blockIdx.z >> 4, ch = blockIdx.z & 15;
  const size_t tok0 = (size_t)b*SEQ + (size_t)ch*CHUNK_SZ + (size_t)qt*128;
  const size_t bch0 = (size_t)b*SEQ + (size_t)ch*CHUNK_SZ;   // local K/V token base
  u16 (* __restrict__ Pw)[72] = PwAll[w];

  // Q fragments straight from global (B-operand: col=q=lr, d contiguous)
  bf16x8 qf[2][2];
  #pragma unroll
  for (int r=0;r<2;r++)
    #pragma unroll
    for (int kk=0;kk<2;kk++)
      qf[r][kk] = *reinterpret_cast<const bf16x8*>(
          &Qb[(tok0 + w*32 + r*16 + lr)*D_MODEL + (size_t)h*HEAD_DIM + kk*32 + lg*8]);

  float m_run[2] = {-INFINITY, -INFINITY};
  float l_run[2] = {0.f, 0.f};
  f32x4 of[2][4];
  #pragma unroll
  for (int r=0;r<2;r++)
    #pragma unroll
    for (int c=0;c<4;c++) of[r][c] = f32x4{0.f,0.f,0.f,0.f};

  // ---- landmark tile (32 keys), staged directly ----
  {
    const size_t lmrow0 = (size_t)TOK + (size_t)b*N_LM;
    int key = t >> 3, dc = (t & 7) << 3;          // 32 keys x 64 d
    *reinterpret_cast<bf16x8*>(&Ks[key][dc]) = *reinterpret_cast<const bf16x8*>(
        &Kb[(lmrow0 + key)*D_MODEL + (size_t)h*HEAD_DIM + dc]);
    int d = t >> 2, kc = (t & 3) << 3;            // 64 d x 32 keys
    *reinterpret_cast<bf16x8*>(&Vs[d][kc]) = *reinterpret_cast<const bf16x8*>(
        &Vt[((size_t)h*HEAD_DIM + d)*MKV_PAD + lmrow0 + kc]);
    __syncthreads();
    attn_compute<32>(lr, lg, Ks, Vs, Pw, qf, m_run, l_run, of);
  }

  // ---- 8 local tiles of 64 keys, reg-prefetched (T14 split) ----
  bf16x8 kreg[2], vreg[2];
  const int key0 = t >> 3, dc0 = (t & 7) << 3;    // K: rows key0, key0+32
  const int d0 = t >> 3, kc0 = (t & 7) << 3;      // V: rows d0, d0+32
  {
    size_t col0 = bch0;                            // tile 0
    kreg[0] = *reinterpret_cast<const bf16x8*>(&Kb[(col0 + key0)*D_MODEL + (size_t)h*HEAD_DIM + dc0]);
    kreg[1] = *reinterpret_cast<const bf16x8*>(&Kb[(col0 + key0 + 32)*D_MODEL + (size_t)h*HEAD_DIM + dc0]);
    vreg[0] = *reinterpret_cast<const bf16x8*>(&Vt[((size_t)h*HEAD_DIM + d0)*MKV_PAD + col0 + kc0]);
    vreg[1] = *reinterpret_cast<const bf16x8*>(&Vt[((size_t)h*HEAD_DIM + d0 + 32)*MKV_PAD + col0 + kc0]);
  }
  for (int tl = 0; tl < 8; ++tl){
    __syncthreads();   // previous tile's LDS reads done
    *reinterpret_cast<bf16x8*>(&Ks[key0][dc0])      = kreg[0];
    *reinterpret_cast<bf16x8*>(&Ks[key0 + 32][dc0]) = kreg[1];
    *reinterpret_cast<bf16x8*>(&Vs[d0][kc0])        = vreg[0];
    *reinterpret_cast<bf16x8*>(&Vs[d0 + 32][kc0])   = vreg[1];
    __syncthreads();
    if (tl < 7){
      size_t col0 = bch0 + (size_t)(tl+1)*64;
      kreg[0] = *reinterpret_cast<const bf16x8*>(&Kb[(col0 + key0)*D_MODEL + (size_t)h*HEAD_DIM + dc0]);
      kreg[1] = *reinterpret_cast<const bf16x8*>(&Kb[(col0 + key0 + 32)*D_MODEL + (size_t)h*HEAD_DIM + dc0]);
      vreg[0] = *reinterpret_cast<const bf16x8*>(&Vt[((size_t)h*HEAD_DIM + d0)*MKV_PAD + col0 + kc0]);
      vreg[1] = *reinterpret_cast<const bf16x8*>(&Vt[((size_t)h*HEAD_DIM + d0 + 32)*MKV_PAD + col0 + kc0]);
    }
    attn_compute<64>(lr, lg, Ks, Vs, Pw, qf, m_run, l_run, of);
  }

  // ---- epilogue: O^T lanes (col=q=lr, row=d) -> AO[token][h*64+d] ----
  #pragma unroll
  for (int r=0;r<2;r++){
    float inv = 1.f / l_run[r];
    size_t row = (tok0 + w*32 + r*16 + lr)*D_MODEL + (size_t)h*HEAD_DIM;
    #pragma unroll
    for (int c=0;c<4;c++){
      ushort4 pk;
      pk.x = f2bf(of[r][c][0]*inv); pk.y = f2bf(of[r][c][1]*inv);
      pk.z = f2bf(of[r][c][2]*inv); pk.w = f2bf(of[r][c][3]*inv);
      *reinterpret_cast<ushort4*>(&AO[row + c*16 + lg*4]) = pk;
    }
  }
}

// ---------------- launch ----------------
extern "C" void kernel_launch(void* const* d_in, const int* in_sizes, int n_in,
                              void* d_out, int out_size, void* d_ws, size_t ws_size,
                              hipStream_t stream) {
  const float* x  = (const float*)d_in[0];
  const float* Wq = (const float*)d_in[1];
  const float* bq = (const float*)d_in[2];
  const float* Wk = (const float*)d_in[3];
  const float* bk = (const float*)d_in[4];
  const float* Wv = (const float*)d_in[5];
  const float* bv = (const float*)d_in[6];
  const float* Wo = (const float*)d_in[7];
  const float* bo = (const float*)d_in[8];
  float* out = (float*)d_out;

  // workspace layout (bytes)
  const size_t XCAT_OFF = 0;                       // 16512*768*2 = 25362432
  const size_t Q_OFF    = 25362432;                // 16384*768*2 = 25165824
  const size_t K_OFF    = 50528256;                // 25362432
  const size_t VT_OFF   = 75890688;                // 768*16512*2 = 25362432 (V^T: [feat][token])
  const size_t AO_OFF   = 101253120;               // 25165824
  const size_t WQ_OFF   = 126418944;               // 1179648
  const size_t WK_OFF   = 127598592;
  const size_t WV_OFF   = 128778240;
  const size_t WO_OFF   = 129957888;
  const size_t TOTAL    = 131137536;
  if (ws_size < TOTAL) return;

  char* ws = (char*)d_ws;
  u16* xcat = (u16*)(ws + XCAT_OFF);
  u16* Qb   = (u16*)(ws + Q_OFF);
  u16* Kb   = (u16*)(ws + K_OFF);
  u16* Vt   = (u16*)(ws + VT_OFF);
  u16* AO   = (u16*)(ws + AO_OFF);
  u16* wqb  = (u16*)(ws + WQ_OFF);
  u16* wkb  = (u16*)(ws + WK_OFF);
  u16* wvb  = (u16*)(ws + WV_OFF);
  u16* wob  = (u16*)(ws + WO_OFF);

  dim3 blk(256);
  cvt4_kernel<<<dim3(2304), blk, 0, stream>>>(Wq, Wk, Wv, Wo, wqb, wkb, wvb, wob);
  build_xcat_kernel<<<dim3(4096), blk, 0, stream>>>(x, xcat);
  landmark_kernel<<<dim3(64), blk, 0, stream>>>(x, xcat);

  // Q (pre-scaled into exp2 domain), K, V^T
  gemm_bt_kernel<0,0><<<dim3(128, 6), blk, 0, stream>>>(xcat, wqb, bq, (void*)Qb, D_MODEL, QSCALE);
  gemm_bt_kernel<0,0><<<dim3(129, 6), blk, 0, stream>>>(xcat, wkb, bk, (void*)Kb, D_MODEL, 1.f);
  gemm_bt_kernel<0,1><<<dim3(6, 129), blk, 0, stream>>>(wvb, xcat, bv, (void*)Vt, MKV_PAD, 1.f);

  attn_kernel<<<dim3(4, 12, 32), blk, 0, stream>>>(Qb, Kb, Vt, AO);

  gemm_bt_kernel<1,0><<<dim3(128, 6), blk, 0, stream>>>(AO, wob, bo, (void*)out, D_MODEL, 1.f);
}